// Round 1
// baseline (300.843 us; speedup 1.0000x reference)
//
#include <hip/hip_runtime.h>
#include <cstdint>
#include <cstddef>

#define BPTS    131072
#define D_DIM   128
#define G_GR    128
#define NL      8
#define GD      (G_GR * D_DIM)       // 16384 floats = 64 KiB
#define NBLK    512                  // heavy-pass blocks: 2/CU, 16 waves/CU
#define TPB     512                  // 8 waves
#define PPB     (BPTS / NBLK)        // 256 contiguous points per block
#define PPW     (PPB / 8)            // 32 contiguous points per wave
#define DRB     16                   // dpart pre-reduce blocks

// ---------------------------------------------------------------------------
// k_centroid: stream X linearly (coalesced 1KB/point bursts), accumulate
// per-group sums into LDS bins[G][D] via ds_add_f32. No sort, no perm.
// Writes per-block partials (deterministic int hist partials for counts).
// ---------------------------------------------------------------------------
__global__ __launch_bounds__(TPB) void k_centroid(const float4* __restrict__ X4,
                                                  const int* __restrict__ sub,
                                                  const int* __restrict__ lab,
                                                  float* __restrict__ cpart,
                                                  int* __restrict__ hpart) {
    __shared__ float bins[GD];        // 64 KiB
    __shared__ int   hist[G_GR];
    int t = threadIdx.x, blk = blockIdx.x;
    int lane = t & 63, w = t >> 6;

    for (int i = t; i < GD; i += TPB) bins[i] = 0.f;
    if (t < G_GR) hist[t] = 0;

    int base = blk * PPB + w * PPW;           // wave's 32 contiguous points
    int pl = base + (lane & 31);
    int gv = sub[pl] * NL + lab[pl];          // lane l<32 holds g(base+l)
    __syncthreads();

    for (int it = 0; it < PPW / 8; ++it) {
        int p0 = base + it * 8;
        float4 x[8];
#pragma unroll
        for (int u = 0; u < 8; ++u)
            x[u] = X4[(size_t)(p0 + u) * 64 + lane];
#pragma unroll
        for (int u = 0; u < 8; ++u) {
            int g = __shfl(gv, it * 8 + u);
            float4 v = x[u];
            v.x += __shfl_xor(v.x, 32);       // fold view1 into view0 lanes
            v.y += __shfl_xor(v.y, 32);
            v.z += __shfl_xor(v.z, 32);
            v.w += __shfl_xor(v.w, 32);
            if (lane < 32) {
                float* b = &bins[g * D_DIM + lane * 4];
                atomicAdd(b + 0, v.x);
                atomicAdd(b + 1, v.y);
                atomicAdd(b + 2, v.z);
                atomicAdd(b + 3, v.w);
            } else if (lane == 32) {
                atomicAdd(&hist[g], 1);
            }
        }
    }
    __syncthreads();
    for (int i = t; i < GD; i += TPB)
        cpart[(size_t)blk * GD + i] = bins[i];
    if (t < G_GR) hpart[blk * G_GR + t] = hist[t];
}

// ---------------------------------------------------------------------------
// k_reduce: centroid[g][d] = sum_b cpart[b][g][d] / (2n); publishes countsf.
// Grid = 128 blocks (one per group), 512 threads (4-way b-parallel).
// ---------------------------------------------------------------------------
__global__ __launch_bounds__(512) void k_reduce(const float* __restrict__ cpart,
                                                const int* __restrict__ hpart,
                                                float* __restrict__ centroid,
                                                float* __restrict__ countsf) {
    __shared__ float red[4][D_DIM];
    __shared__ int   hred[64];
    __shared__ float cf2s;
    int g = blockIdx.x, t = threadIdx.x;
    int d = t & 127, bs = t >> 7;

    float acc = 0.f;
#pragma unroll 4
    for (int b = bs; b < NBLK; b += 4)
        acc += cpart[(size_t)b * GD + g * D_DIM + d];
    red[bs][d] = acc;

    if (t < 64) {
        int hacc = 0;
        for (int b = t; b < NBLK; b += 64) hacc += hpart[b * G_GR + g];
        hred[t] = hacc;
    }
    __syncthreads();
    if (t == 0) {
        int n = 0;
        for (int i = 0; i < 64; ++i) n += hred[i];
        cf2s = 2.f * (float)n;
        countsf[g] = cf2s;
    }
    __syncthreads();
    if (t < D_DIM) {
        float v = red[0][t] + red[1][t] + red[2][t] + red[3][t];
        float cf2 = cf2s;
        centroid[g * D_DIM + t] = (cf2 > 0.f) ? v / cf2 : 0.f;
    }
}

// ---------------------------------------------------------------------------
// k_distn: stream X linearly again; centroid table staged in LDS (64 KiB).
// Per point: per-view ||x-c||^2 via 32-lane butterfly, sqrt(sqrt(d)),
// fold views, accumulate per-group in LDS bins. Block partials to dpart.
// ---------------------------------------------------------------------------
__global__ __launch_bounds__(TPB) void k_distn(const float4* __restrict__ X4,
                                               const int* __restrict__ sub,
                                               const int* __restrict__ lab,
                                               const float* __restrict__ centroid,
                                               float* __restrict__ dpart) {
    __shared__ float cen[GD];         // 64 KiB
    __shared__ float dbin[G_GR];
    int t = threadIdx.x, blk = blockIdx.x;
    int lane = t & 63, w = t >> 6;

    for (int i = t; i < GD; i += TPB) cen[i] = centroid[i];
    if (t < G_GR) dbin[t] = 0.f;

    int base = blk * PPB + w * PPW;
    int pl = base + (lane & 31);
    int gv = sub[pl] * NL + lab[pl];
    __syncthreads();

    const float4* cen4 = (const float4*)cen;
    int ci = lane & 31;

    for (int it = 0; it < PPW / 8; ++it) {
        int p0 = base + it * 8;
        float4 x[8];
#pragma unroll
        for (int u = 0; u < 8; ++u)
            x[u] = X4[(size_t)(p0 + u) * 64 + lane];
#pragma unroll
        for (int u = 0; u < 8; ++u) {
            int g = __shfl(gv, it * 8 + u);
            float4 c = cen4[g * 32 + ci];   // lanes 0-31 linear, 32-63 dup: free
            float dx = x[u].x - c.x, dy = x[u].y - c.y;
            float dz = x[u].z - c.z, dw = x[u].w - c.w;
            float d = dx * dx + dy * dy + dz * dz + dw * dw;
#pragma unroll
            for (int m = 1; m <= 16; m <<= 1) d += __shfl_xor(d, m);
            float s = sqrtf(sqrtf(d));      // sqrt(||x-c||), per view
            s += __shfl_xor(s, 32);         // view0 + view1
            if (lane == 0) atomicAdd(&dbin[g], s);
        }
    }
    __syncthreads();
    if (t < G_GR) dpart[blk * G_GR + t] = dbin[t];
}

// ---------------------------------------------------------------------------
// k_dred: fold 512 dpart rows to 16 (coalesced), so k_final stays cheap.
// ---------------------------------------------------------------------------
__global__ __launch_bounds__(256) void k_dred(const float* __restrict__ dpart,
                                              float* __restrict__ dmid) {
    __shared__ float red[2][G_GR];
    int t = threadIdx.x, blk = blockIdx.x;
    int d = t & 127, h = t >> 7;
    int b0 = blk * (NBLK / DRB);
    float acc = 0.f;
    for (int b = b0 + h; b < b0 + NBLK / DRB; b += 2)
        acc += dpart[b * G_GR + d];
    red[h][d] = acc;
    __syncthreads();
    if (t < G_GR) dmid[blk * G_GR + t] = red[0][t] + red[1][t];
}

// ---------------------------------------------------------------------------
// k_final: single block, 128 threads (thread t = group t). Unchanged logic.
// ---------------------------------------------------------------------------
__global__ __launch_bounds__(128) void k_final(const float* __restrict__ dmid,
                                               const float* __restrict__ countsf,
                                               const float* __restrict__ centroid,
                                               float* __restrict__ out) {
    __shared__ float srt[G_GR];
    __shared__ float red[G_GR];
    __shared__ float coc[D_DIM];
    int t = threadIdx.x;

    float ds = 0.f;
    for (int b = 0; b < DRB; ++b) ds += dmid[b * G_GR + t];
    float cnt  = countsf[t];
    float dens = (cnt > 1.f) ? (ds / cnt) / logf(cnt + 10.f) : 0.f;

    red[t] = dens;
    __syncthreads();
    for (int s = 64; s > 0; s >>= 1) {
        if (t < s) red[t] = fmaxf(red[t], red[t + s]);
        __syncthreads();
    }
    float dmax = red[0];
    __syncthreads();
    if (!(cnt > 1.f)) dens = dmax;

    // bitonic sort ascending
    srt[t] = dens;
    __syncthreads();
    for (int k = 2; k <= G_GR; k <<= 1) {
        for (int j = k >> 1; j > 0; j >>= 1) {
            int ixj = t ^ j;
            if (ixj > t) {
                float a = srt[t], b = srt[ixj];
                bool up = ((t & k) == 0);
                if ((a > b) == up) { srt[t] = b; srt[ixj] = a; }
            }
            __syncthreads();
        }
    }
    double p10 = 0.10 * 127.0, p90 = 0.90 * 127.0;
    int   i10 = (int)p10,           i90 = (int)p90;
    float f10 = (float)(p10 - i10), f90 = (float)(p90 - i90);
    float lo = srt[i10] + f10 * (srt[i10 + 1] - srt[i10]);
    float hi = srt[i90] + f90 * (srt[i90 + 1] - srt[i90]);
    dens = fminf(fmaxf(dens, lo), hi);

    red[t] = dens;
    __syncthreads();
    for (int s = 64; s > 0; s >>= 1) {
        if (t < s) red[t] += red[t + s];
        __syncthreads();
    }
    float dmean = red[0] / 128.f;
    __syncthreads();
    dens = 0.1f * dens / dmean;

    float cs = 0.f;
    for (int g = 0; g < G_GR; ++g) cs += centroid[g * D_DIM + t];
    coc[t] = cs / 128.f;
    __syncthreads();

    float dot = 0.f;
    for (int d = 0; d < D_DIM; ++d) dot += centroid[t * D_DIM + d] * coc[d];
    float sim = expf(dot / dens);

    red[t] = sim;
    __syncthreads();
    for (int s = 64; s > 0; s >>= 1) {
        if (t < s) red[t] = fmaxf(red[t], red[t + s]);
        __syncthreads();
    }
    float smax = red[0];
    __syncthreads();
    red[t] = sim - smax;
    __syncthreads();
    for (int s = 64; s > 0; s >>= 1) {
        if (t < s) red[t] += red[t + s];
        __syncthreads();
    }
    if (t == 0) out[0] = -(red[0] / 128.f);
}

// ---------------------------------------------------------------------------
extern "C" void kernel_launch(void* const* d_in, const int* in_sizes, int n_in,
                              void* d_out, int out_size, void* d_ws, size_t ws_size,
                              hipStream_t stream) {
    const float4* X4      = (const float4*)d_in[0];
    const int*    subject = (const int*)d_in[1];
    const int*    labels  = (const int*)d_in[2];
    float*        out     = (float*)d_out;
    char*         ws      = (char*)d_ws;

    size_t o = 0;
    float* cpart    = (float*)(ws + o); o += (size_t)NBLK * GD * 4;     // 32 MiB
    int*   hpart    = (int*)(ws + o);   o += (size_t)NBLK * G_GR * 4;   // 256 KiB
    float* centroid = (float*)(ws + o); o += (size_t)GD * 4;            // 64 KiB
    float* countsf  = (float*)(ws + o); o += 512;
    float* dpart    = (float*)(ws + o); o += (size_t)NBLK * G_GR * 4;   // 256 KiB
    float* dmid     = (float*)(ws + o); o += (size_t)DRB * G_GR * 4;    // 8 KiB

    k_centroid<<<NBLK, TPB, 0, stream>>>(X4, subject, labels, cpart, hpart);
    k_reduce  <<<G_GR, 512, 0, stream>>>(cpart, hpart, centroid, countsf);
    k_distn   <<<NBLK, TPB, 0, stream>>>(X4, subject, labels, centroid, dpart);
    k_dred    <<<DRB, 256, 0, stream>>>(dpart, dmid);
    k_final   <<<1, 128, 0, stream>>>(dmid, countsf, centroid, out);
}